// Round 6
// baseline (1875.381 us; speedup 1.0000x reference)
//
#include <hip/hip_runtime.h>
#include <math.h>

#define HID 256
#define NCLASS 5
#define DEPTH 11
#define NB 128
#define NN 2047

typedef __attribute__((ext_vector_type(8))) short bf16x8_t;
typedef __attribute__((ext_vector_type(4))) float f32x4_t;

__device__ __forceinline__ float bf2f(unsigned short u) {
    return __uint_as_float(((unsigned)u) << 16);
}
__device__ __forceinline__ unsigned short f2bf(float f) {
    unsigned x = __float_as_uint(f);
    unsigned r = (x + 0x7fff + ((x >> 16) & 1)) >> 16;   // RNE
    return (unsigned short)r;
}
__device__ __forceinline__ float sigmoidf_(float x) {
    return __fdividef(1.0f, 1.0f + __expf(-x));
}
// fast tanh: 1 - 2/(e^{2x}+1). NaN-safe at saturation (e->inf => 1, e->0 => -1).
__device__ __forceinline__ float tanhf_(float x) {
    return 1.0f - __fdividef(2.0f, __expf(2.0f * x) + 1.0f);
}

// ---------------- Wcat: (1280 n, 768 k) bf16, gate-major: n = g*256 + ch ----------------
// gate g: 0=i,1=o,2=u,3=f0,4=f1 ; k: [0,256)=W_g, [256,512)=U left, [512,768)=U right
__global__ __launch_bounds__(256)
void prep_wcat(const float* __restrict__ W_i, const float* __restrict__ U_i,
               const float* __restrict__ W_f, const float* __restrict__ U_f,
               const float* __restrict__ W_o, const float* __restrict__ U_o,
               const float* __restrict__ W_u, const float* __restrict__ U_u,
               unsigned short* __restrict__ Wcat)
{
    int idx = blockIdx.x * 256 + threadIdx.x;     // 0 .. 1280*768-1
    int k = idx % 768;
    int n = idx / 768;
    int g = n >> 8;
    int ch = n & 255;
    int seg = k >> 8;
    int kk = k & 255;
    float v;
    if (seg == 0) {
        const float* W = (g == 0) ? W_i : (g == 1) ? W_o : (g == 2) ? W_u : W_f;
        v = W[ch * 256 + kk];
    } else {
        int side = seg - 1;
        if (g == 0)      v = U_i[(side * 256 + ch) * 256 + kk];
        else if (g == 1) v = U_o[(side * 256 + ch) * 256 + kk];
        else if (g == 2) v = U_u[(side * 256 + ch) * 256 + kk];
        else             v = U_f[(((g - 3) * 2 + side) * 256 + ch) * 256 + kk];
    }
    Wcat[(size_t)n * 768 + k] = f2bf(v);
}

// ---------------- x cast fp32 -> bf16 ----------------
__global__ __launch_bounds__(256)
void cast_x_kernel(const float* __restrict__ x, unsigned short* __restrict__ xb)
{
    size_t i = ((size_t)blockIdx.x * 256 + threadIdx.x) * 8;
    float4 a = *(const float4*)(x + i);
    float4 b = *(const float4*)(x + i + 4);
    unsigned short o[8] = {f2bf(a.x), f2bf(a.y), f2bf(a.z), f2bf(a.w),
                           f2bf(b.x), f2bf(b.y), f2bf(b.z), f2bf(b.w)};
    *(uint4*)(xb + i) = *(uint4*)o;
}

// ---------------- fused level GEMM + LSTM epilogue, DIRECT-TO-REGISTER ----------------
// No LDS, no barriers, no vmcnt choreography. Rationale: the MFMA fragment
// layout (lane = (row p = lane&15, k-quad = lane>>4), 16B contiguous per lane)
// maps DIRECTLY onto contiguous global_load_dwordx4 from both xb/hA (k-major
// rows) and Wcat (k-major n-rows) — identical coalescing to the old staging
// loads. B (2MB Wcat) is permanently L2-resident; A rows are shared only by
// the 4 chblk-siblings, which the XCD swizzle co-locates on one L2. LDS
// staging bought reuse of a non-binding resource (L2 BW) at the price of a
// barrier-lockstep structure stuck at ~20% MfmaUtil across 3 schedule rounds.
// Each wave: 64 rows x (NG gates x 16 ch), acc[4][NG], explicit 2-deep
// register pipeline with NAMED frag sets (static indexing only — runtime-
// indexed frag arrays go to scratch). Full unroll: compile-time k0 folds into
// load immediate offsets (<4KB), zero address arithmetic in the loop.
template<int NG, int NK, bool LEAF>
__global__ __launch_bounds__(512, LEAF ? 3 : 2)
void level_gemm(const unsigned short* __restrict__ xb,
                const unsigned short* __restrict__ hA,       // (rows,512) [hL|hR]; null if LEAF
                const unsigned short* __restrict__ Wcat,
                const float* __restrict__ c_child,           // (child rows,256); null if LEAF
                const float* __restrict__ b_i, const float* __restrict__ b_o,
                const float* __restrict__ b_u, const float* __restrict__ b_f,
                float* __restrict__ c_out,                   // (rows,256)
                unsigned short* __restrict__ hA_parent,      // (rows/2,512) or null
                unsigned short* __restrict__ h_all,          // (B,NN,256) bf16
                int lgM, int nrb)
{
    const int tid  = threadIdx.x;
    const int lane = tid & 63;
    const int w    = tid >> 6;
    const int quad = lane >> 4, p = lane & 15;
    const int rh = w & 1, cq = w >> 1;

    // ---- XCD-sibling swizzle: 4 chblk-siblings of a rowblock -> same XCD ----
    int chblk, rb;
    {
        int bid = blockIdx.x;
        if ((nrb & 7) == 0) {
            int x = bid & 7, sl = bid >> 3;
            chblk = sl & 3;
            rb = x + 8 * (sl >> 2);
        } else {
            chblk = bid & 3;
            rb = bid >> 2;
        }
    }
    const int R0 = rb * 128;
    const int M = 1 << lgM, s = M - 1;

    // ---- per-lane fragment bases (loop-invariant; k0 added as imm offset) ----
    // A: frag mi covers rows (rh*4+mi)*16 + p; lane loads 16B at k = k0 + quad*8
    const unsigned short* ax[4];
    const unsigned short* ah[4];
    #pragma unroll
    for (int mi = 0; mi < 4; ++mi) {
        const int arow = R0 + (rh * 4 + mi) * 16 + p;
        const int ab = arow >> lgM, am = arow & (M - 1);
        ax[mi] = xb + ((size_t)ab * NN + s + am) * 256 + quad * 8;
        ah[mi] = LEAF ? ax[mi] : hA + (size_t)arow * 512 + quad * 8;
    }
    // B: gate j, n = j*256 + chblk*64 + cq*16 + p
    const unsigned short* bb[NG];
    #pragma unroll
    for (int j = 0; j < NG; ++j) {
        int n = j * 256 + chblk * 64 + cq * 16 + p;
        bb[j] = Wcat + (size_t)n * 768 + quad * 8;
    }

    f32x4_t acc[4][NG];
    #pragma unroll
    for (int mi = 0; mi < 4; ++mi)
        #pragma unroll
        for (int j = 0; j < NG; ++j)
            acc[mi][j] = (f32x4_t){0.f, 0.f, 0.f, 0.f};

    bf16x8_t fa0[4], fa1[4];
    bf16x8_t fb0[NG], fb1[NG];

    #define LOAD_A(k0, fa)                                                        \
        _Pragma("unroll")                                                         \
        for (int mi = 0; mi < 4; ++mi) {                                          \
            const unsigned short* srcA = (LEAF || (k0) < 256) ? (ax[mi] + (k0))   \
                                                  : (ah[mi] + ((k0) - 256));      \
            fa[mi] = *(const bf16x8_t*)srcA;                                      \
        }
    #define LOAD_B(k0, fb)                                                        \
        _Pragma("unroll")                                                         \
        for (int j = 0; j < NG; ++j)                                              \
            fb[j] = *(const bf16x8_t*)(bb[j] + (k0));
    #define COMPUTE(fa, fb)                                                       \
        _Pragma("unroll")                                                         \
        for (int j = 0; j < NG; ++j)                                              \
            _Pragma("unroll")                                                     \
            for (int mi = 0; mi < 4; ++mi)                                        \
                acc[mi][j] = __builtin_amdgcn_mfma_f32_16x16x32_bf16(             \
                    fa[mi], fb[j], acc[mi][j], 0, 0, 0);

    // prologue: fill both pipeline stages
    LOAD_A(0, fa0); LOAD_B(0, fb0);
    LOAD_A(32, fa1); LOAD_B(32, fb1);

    #pragma unroll
    for (int st = 0; st < NK; st += 2) {
        COMPUTE(fa0, fb0);
        if (st + 2 < NK) { LOAD_A((st + 2) * 32, fa0); LOAD_B((st + 2) * 32, fb0); }
        COMPUTE(fa1, fb1);
        if (st + 3 < NK) { LOAD_A((st + 3) * 32, fa1); LOAD_B((st + 3) * 32, fb1); }
    }
    #undef LOAD_A
    #undef LOAD_B
    #undef COMPUTE

    // ---- fused epilogue: each lane owns all NG gates for (16 rows x 1 channel) ----
    const int gch = chblk * 64 + cq * 16 + p;
    const float bi = b_i[gch], bo = b_o[gch], bu = b_u[gch];
    const float bfv = LEAF ? 0.f : b_f[gch];

    #pragma unroll
    for (int mi = 0; mi < 4; ++mi) {
        const int rowq = R0 + rh * 64 + mi * 16 + quad * 4;
        // batch the c_child loads for this mi (8 independent loads in flight)
        float cl[4], cr[4];
        if (!LEAF) {
            #pragma unroll
            for (int reg = 0; reg < 4; ++reg) {
                const int grow = rowq + reg;
                const int b = grow >> lgM, m = grow & (M - 1);
                const float* crow = c_child + ((size_t)b * (M << 1) + 2 * m) * 256 + gch;
                cl[reg] = crow[0];
                cr[reg] = crow[256];
            }
        }
        #pragma unroll
        for (int reg = 0; reg < 4; ++reg) {
            const int grow = rowq + reg;
            const int b = grow >> lgM, m = grow & (M - 1);
            float ig = sigmoidf_(acc[mi][0][reg] + bi);
            float og = sigmoidf_(acc[mi][1][reg] + bo);
            float ug = tanhf_(acc[mi][2][reg] + bu);
            float c;
            if (LEAF) {
                c = ig * ug;
            } else {
                float f0 = sigmoidf_(acc[mi][3][reg] + bfv);
                float f1 = sigmoidf_(acc[mi][4][reg] + bfv);
                c = fmaf(f0, cl[reg], fmaf(f1, cr[reg], ig * ug));
            }
            float h = og * tanhf_(c);
            c_out[(size_t)grow * 256 + gch] = c;
            unsigned short hb = f2bf(h);
            h_all[((size_t)b * NN + s + m) * 256 + gch] = hb;
            if (hA_parent)
                hA_parent[((size_t)b * (M >> 1) + (m >> 1)) * 512 + (m & 1) * 256 + gch] = hb;
        }
    }
}

// ---------------- classifier softmax over all nodes ----------------
__global__ __launch_bounds__(256)
void softmax_kernel(const unsigned short* __restrict__ h_all,
                    const float* __restrict__ W_s, const float* __restrict__ b_s,
                    float* __restrict__ out)
{
    __shared__ float Ws[5 * 256];
    int tid = threadIdx.x;
    for (int i = tid; i < 1280; i += 256) Ws[i] = W_s[i];
    __syncthreads();

    int r = tid >> 3, q = tid & 7;
    size_t row = (size_t)blockIdx.x * 32 + r;
    const unsigned short* hp = h_all + row * 256 + q * 32;

    float p0 = 0.f, p1 = 0.f, p2 = 0.f, p3 = 0.f, p4 = 0.f;
    #pragma unroll
    for (int kk = 0; kk < 32; kk += 8) {
        uint4 raw = *(const uint4*)(hp + kk);
        unsigned short hu[8];
        *(uint4*)hu = raw;
        #pragma unroll
        for (int e = 0; e < 8; ++e) {
            float hvv = bf2f(hu[e]);
            int k = q * 32 + kk + e;
            p0 = fmaf(Ws[k],        hvv, p0);
            p1 = fmaf(Ws[256 + k],  hvv, p1);
            p2 = fmaf(Ws[512 + k],  hvv, p2);
            p3 = fmaf(Ws[768 + k],  hvv, p3);
            p4 = fmaf(Ws[1024 + k], hvv, p4);
        }
    }
    #pragma unroll
    for (int off = 4; off; off >>= 1) {
        p0 += __shfl_down(p0, off, 8);
        p1 += __shfl_down(p1, off, 8);
        p2 += __shfl_down(p2, off, 8);
        p3 += __shfl_down(p3, off, 8);
        p4 += __shfl_down(p4, off, 8);
    }
    if (q == 0) {
        float l0 = p0 + b_s[0], l1 = p1 + b_s[1], l2 = p2 + b_s[2];
        float l3 = p3 + b_s[3], l4 = p4 + b_s[4];
        float mx = fmaxf(fmaxf(fmaxf(l0, l1), fmaxf(l2, l3)), l4);
        float e0 = __expf(l0 - mx), e1 = __expf(l1 - mx), e2 = __expf(l2 - mx);
        float e3 = __expf(l3 - mx), e4 = __expf(l4 - mx);
        float inv = 1.0f / (e0 + e1 + e2 + e3 + e4);
        float* orow = out + row * NCLASS;
        orow[0] = e0 * inv;
        orow[1] = e1 * inv;
        orow[2] = e2 * inv;
        orow[3] = e3 * inv;
        orow[4] = e4 * inv;
    }
}

extern "C" void kernel_launch(void* const* d_in, const int* in_sizes, int n_in,
                              void* d_out, int out_size, void* d_ws, size_t ws_size,
                              hipStream_t stream) {
    const float* x   = (const float*)d_in[0];
    const float* W_i = (const float*)d_in[1];
    const float* U_i = (const float*)d_in[2];
    const float* b_i = (const float*)d_in[3];
    const float* W_f = (const float*)d_in[4];
    const float* U_f = (const float*)d_in[5];
    const float* b_f = (const float*)d_in[6];
    const float* W_o = (const float*)d_in[7];
    const float* U_o = (const float*)d_in[8];
    const float* b_o = (const float*)d_in[9];
    const float* W_u = (const float*)d_in[10];
    const float* U_u = (const float*)d_in[11];
    const float* b_u = (const float*)d_in[12];
    const float* W_s = (const float*)d_in[13];
    const float* b_s = (const float*)d_in[14];
    float* out = (float*)d_out;

    char* p = (char*)d_ws;
    unsigned short* Wcat  = (unsigned short*)p; p += 2097152;       // 1280*768*2
    unsigned short* xb    = (unsigned short*)p; p += 134152192;     // 128*2047*256*2
    unsigned short* h_all = (unsigned short*)p; p += 134152192;
    unsigned short* hA0   = (unsigned short*)p; p += 33554432;      // even-level hA input
    unsigned short* hA1   = (unsigned short*)p; p += 67108864;      // odd-level hA input
    float* cb0 = (float*)p; p += 134217728;                         // even-level c
    float* cb1 = (float*)p; p += 67108864;                          // odd-level c

    prep_wcat<<<3840, 256, 0, stream>>>(W_i, U_i, W_f, U_f, W_o, U_o, W_u, U_u, Wcat);
    cast_x_kernel<<<32752, 256, 0, stream>>>(x, xb);

    for (int lvl = DEPTH - 1; lvl >= 0; --lvl) {
        float* c_o        = (lvl & 1) ? cb1 : cb0;
        const float* c_ch = ((lvl + 1) & 1) ? cb1 : cb0;
        const unsigned short* hA_this = (lvl & 1) ? hA1 : hA0;
        unsigned short* hA_par = (lvl > 0) ? (((lvl - 1) & 1) ? hA1 : hA0) : nullptr;

        const int nrb = 1 << lvl;                     // rows/128
        if (lvl == DEPTH - 1) {
            level_gemm<3, 8, true><<<dim3(4 * nrb), 512, 0, stream>>>(
                xb, nullptr, Wcat, nullptr, b_i, b_o, b_u, b_f,
                c_o, hA_par, h_all, lvl, nrb);
        } else {
            level_gemm<5, 24, false><<<dim3(4 * nrb), 512, 0, stream>>>(
                xb, hA_this, Wcat, c_ch, b_i, b_o, b_u, b_f,
                c_o, hA_par, h_all, lvl, nrb);
        }
    }

    softmax_kernel<<<8188, 256, 0, stream>>>(h_all, W_s, b_s, out);
}

// Round 7
// 1138.530 us; speedup vs baseline: 1.6472x; 1.6472x over previous
//
#include <hip/hip_runtime.h>
#include <math.h>

#define HID 256
#define NCLASS 5
#define DEPTH 11
#define NB 128
#define NN 2047

typedef __attribute__((ext_vector_type(8))) short bf16x8_t;
typedef __attribute__((ext_vector_type(4))) float f32x4_t;

__device__ __forceinline__ float bf2f(unsigned short u) {
    return __uint_as_float(((unsigned)u) << 16);
}
__device__ __forceinline__ unsigned short f2bf(float f) {
    unsigned x = __float_as_uint(f);
    unsigned r = (x + 0x7fff + ((x >> 16) & 1)) >> 16;   // RNE
    return (unsigned short)r;
}
__device__ __forceinline__ float sigmoidf_(float x) {
    return __fdividef(1.0f, 1.0f + __expf(-x));
}
// fast tanh: 1 - 2/(e^{2x}+1). NaN-safe at saturation (e->inf => 1, e->0 => -1).
__device__ __forceinline__ float tanhf_(float x) {
    return 1.0f - __fdividef(2.0f, __expf(2.0f * x) + 1.0f);
}
// async global->LDS, 16B per lane; LDS dest = wave-uniform base + lane*16
__device__ __forceinline__ void gl_lds16(const void* g, void* l) {
    __builtin_amdgcn_global_load_lds(
        (const __attribute__((address_space(1))) unsigned int*)g,
        (__attribute__((address_space(3))) unsigned int*)l,
        16, 0, 0);
}

// ---------------- Wcat: (1280 n, 768 k) bf16, gate-major: n = g*256 + ch ----------------
// gate g: 0=i,1=o,2=u,3=f0,4=f1 ; k: [0,256)=W_g, [256,512)=U left, [512,768)=U right
__global__ __launch_bounds__(256)
void prep_wcat(const float* __restrict__ W_i, const float* __restrict__ U_i,
               const float* __restrict__ W_f, const float* __restrict__ U_f,
               const float* __restrict__ W_o, const float* __restrict__ U_o,
               const float* __restrict__ W_u, const float* __restrict__ U_u,
               unsigned short* __restrict__ Wcat)
{
    int idx = blockIdx.x * 256 + threadIdx.x;     // 0 .. 1280*768-1
    int k = idx % 768;
    int n = idx / 768;
    int g = n >> 8;
    int ch = n & 255;
    int seg = k >> 8;
    int kk = k & 255;
    float v;
    if (seg == 0) {
        const float* W = (g == 0) ? W_i : (g == 1) ? W_o : (g == 2) ? W_u : W_f;
        v = W[ch * 256 + kk];
    } else {
        int side = seg - 1;
        if (g == 0)      v = U_i[(side * 256 + ch) * 256 + kk];
        else if (g == 1) v = U_o[(side * 256 + ch) * 256 + kk];
        else if (g == 2) v = U_u[(side * 256 + ch) * 256 + kk];
        else             v = U_f[(((g - 3) * 2 + side) * 256 + ch) * 256 + kk];
    }
    Wcat[(size_t)n * 768 + k] = f2bf(v);
}

// ---------------- x cast fp32 -> bf16 ----------------
__global__ __launch_bounds__(256)
void cast_x_kernel(const float* __restrict__ x, unsigned short* __restrict__ xb)
{
    size_t i = ((size_t)blockIdx.x * 256 + threadIdx.x) * 8;
    float4 a = *(const float4*)(x + i);
    float4 b = *(const float4*)(x + i + 4);
    unsigned short o[8] = {f2bf(a.x), f2bf(a.y), f2bf(a.z), f2bf(a.w),
                           f2bf(b.x), f2bf(b.y), f2bf(b.z), f2bf(b.w)};
    *(uint4*)(xb + i) = *(uint4*)o;
}

// ---------------- fused level GEMM + LSTM epilogue, counted-vmcnt pipeline (R2 base) ----
// Block: 512 thr = 8 waves, tile 128 rows x NT*16 cols, BK=32 (=MFMA K).
// K-loop (T3/T4): issue stage(t+1) -> s_waitcnt vmcnt(g) [t landed, t+1 IN
// FLIGHT] -> s_barrier -> compute(t) -> s_barrier. No vmcnt(0) drain in loop.
// A sourcing: k<256 from xb; k in [256,512) from h_all LEFT child row;
// [512,768) RIGHT child row (side is uniform per 32-k step). This removes the
// hA_parent rearranged copy entirely (-134 MB of writes pipeline-wide).
// c: single c_all (B,NN,256) f32 buffer; children at node offset s2+2m.
template<int NG, int NK, bool LEAF>
__global__ __launch_bounds__(512, 4)
void level_gemm(const unsigned short* __restrict__ xb,
                const unsigned short* __restrict__ Wcat,
                float* __restrict__ c_all,                   // (B,NN,256) f32
                unsigned short* __restrict__ h_all,          // (B,NN,256) bf16
                const float* __restrict__ b_i, const float* __restrict__ b_o,
                const float* __restrict__ b_u, const float* __restrict__ b_f,
                int lgM, int nrb)
{
    constexpr int NT = NG * 4;            // n-tiles per block (20 or 12)
    constexpr int BOFF = 8192;            // A region: 8 m-tiles * 1KB
    constexpr int BUFSZ = BOFF + NT * 1024;
    __shared__ __align__(16) char smem[2 * BUFSZ];   // double-buffered

    const int tid  = threadIdx.x;
    const int w    = tid >> 6, lane = tid & 63;
    const int quad = lane >> 4, p = lane & 15;
    const int rh = w & 1, cq = w >> 1;

    // ---- XCD-sibling swizzle: 4 chblk-siblings of a rowblock -> same XCD ----
    int chblk, rb;
    {
        int bid = blockIdx.x;
        if ((nrb & 7) == 0) {
            int x = bid & 7, sl = bid >> 3;
            chblk = sl & 3;
            rb = x + 8 * (sl >> 2);
        } else {
            chblk = bid & 3;
            rb = bid >> 2;
        }
    }
    const int R0 = rb * 128;
    const int M = 1 << lgM, s = M - 1, s2 = 2 * M - 1;

    // ---- per-lane staging source bases (fixed across K-steps) ----
    // A: wave w stages m-tile w; lane covers (row = R0 + w*16 + p, k-sub = quad*8)
    const int arow = R0 + w * 16 + p;
    const int ab = arow >> lgM, am = arow & (M - 1);
    const unsigned short* a_x = xb + ((size_t)ab * NN + s + am) * 256 + quad * 8;
    const unsigned short* a_hL = LEAF ? a_x
        : h_all + ((size_t)ab * NN + s2 + 2 * am) * 256 + quad * 8;
    const unsigned short* a_hR = a_hL + 256;
    // B: wave w stages n-tiles [t0, t0+nbt)
    const int nbt = LEAF ? (w < 4 ? 2 : 1) : (w < 4 ? 3 : 2);
    const int t0  = LEAF ? (w < 4 ? w * 2 : 8 + (w - 4))
                         : (w < 4 ? w * 3 : 12 + (w - 4) * 2);
    const unsigned short* bsrc[3];
    #pragma unroll
    for (int j = 0; j < 3; ++j) {
        int t = t0 + ((j < nbt) ? j : 0);
        int n = (t >> 2) * 256 + chblk * 64 + (t & 3) * 16 + p;
        bsrc[j] = Wcat + (size_t)n * 768 + quad * 8;
    }

    auto stage_step = [&](int k0, char* buf) {
        const unsigned short* asrc =
            (LEAF || k0 < 256) ? (a_x + k0)
            : (k0 < 512 ? (a_hL + (k0 - 256)) : (a_hR + (k0 - 512)));
        gl_lds16(asrc, buf + w * 1024);
        #pragma unroll
        for (int j = 0; j < 3; ++j)
            if (j < nbt) gl_lds16(bsrc[j] + k0, buf + BOFF + (t0 + j) * 1024);
    };

    f32x4_t acc[4][NG];
    #pragma unroll
    for (int mi = 0; mi < 4; ++mi)
        #pragma unroll
        for (int j = 0; j < NG; ++j)
            acc[mi][j] = (f32x4_t){0.f, 0.f, 0.f, 0.f};

    // ---- prologue: issue stage for step 0 into buffer 0 (no wait here) ----
    stage_step(0, smem);
    __builtin_amdgcn_sched_barrier(0);

    for (int step = 0; step < NK; ++step) {
        char* bufc = smem + (size_t)(step & 1) * BUFSZ;
        if (step + 1 < NK) {
            // stage step+1 into the other buffer (async; stays in flight across
            // both barriers and the whole compute phase)
            char* bufn = smem + (size_t)((step + 1) & 1) * BUFSZ;
            stage_step((step + 1) * 32, bufn);
            __builtin_amdgcn_sched_barrier(0);
            // per-wave counted wait: g = 1 (A) + nbt (B) granules per step.
            // Outstanding = 2g (steps t, t+1); vmcnt(g) => step t's loads landed.
            if (nbt == 3)      asm volatile("s_waitcnt vmcnt(4)" ::: "memory");
            else if (nbt == 2) asm volatile("s_waitcnt vmcnt(3)" ::: "memory");
            else               asm volatile("s_waitcnt vmcnt(2)" ::: "memory");
        } else {
            asm volatile("s_waitcnt vmcnt(0)" ::: "memory");
        }
        __builtin_amdgcn_s_barrier();          // all waves' step-t granules visible
        __builtin_amdgcn_sched_barrier(0);

        // compute: 4 m-frags, NG n-frags, 4*NG MFMAs from current buffer
        bf16x8_t af[4];
        #pragma unroll
        for (int mi = 0; mi < 4; ++mi)
            af[mi] = *(const bf16x8_t*)(bufc + ((rh * 4 + mi) * 64 + lane) * 16);
        __builtin_amdgcn_s_setprio(1);
        #pragma unroll
        for (int j = 0; j < NG; ++j) {
            bf16x8_t bfr = *(const bf16x8_t*)(bufc + BOFF + ((j * 4 + cq) * 64 + lane) * 16);
            #pragma unroll
            for (int mi = 0; mi < 4; ++mi)
                acc[mi][j] = __builtin_amdgcn_mfma_f32_16x16x32_bf16(af[mi], bfr, acc[mi][j], 0, 0, 0);
        }
        __builtin_amdgcn_s_setprio(0);
        __builtin_amdgcn_sched_barrier(0);
        __builtin_amdgcn_s_barrier();          // buf(t) free for iter t+1's restage
        __builtin_amdgcn_sched_barrier(0);
    }

    // ---- fused epilogue: each lane owns all NG gates for (16 rows x 1 channel) ----
    const int gch = chblk * 64 + cq * 16 + p;
    const float bi = b_i[gch], bo = b_o[gch], bu = b_u[gch];
    const float bfv = LEAF ? 0.f : b_f[gch];

    #pragma unroll
    for (int mi = 0; mi < 4; ++mi) {
        const int rowq = R0 + rh * 64 + mi * 16 + quad * 4;
        // batch the c_all child loads for this mi (8 independent loads in flight)
        float cl[4], cr[4];
        if (!LEAF) {
            #pragma unroll
            for (int reg = 0; reg < 4; ++reg) {
                const int grow = rowq + reg;
                const int b = grow >> lgM, m = grow & (M - 1);
                const float* crow = c_all + ((size_t)b * NN + s2 + 2 * m) * 256 + gch;
                cl[reg] = crow[0];
                cr[reg] = crow[256];
            }
        }
        #pragma unroll
        for (int reg = 0; reg < 4; ++reg) {
            const int grow = rowq + reg;
            const int b = grow >> lgM, m = grow & (M - 1);
            float ig = sigmoidf_(acc[mi][0][reg] + bi);
            float og = sigmoidf_(acc[mi][1][reg] + bo);
            float ug = tanhf_(acc[mi][2][reg] + bu);
            float c;
            if (LEAF) {
                c = ig * ug;
            } else {
                float f0 = sigmoidf_(acc[mi][3][reg] + bfv);
                float f1 = sigmoidf_(acc[mi][4][reg] + bfv);
                c = fmaf(f0, cl[reg], fmaf(f1, cr[reg], ig * ug));
            }
            float h = og * tanhf_(c);
            c_all[((size_t)b * NN + s + m) * 256 + gch] = c;
            h_all[((size_t)b * NN + s + m) * 256 + gch] = f2bf(h);
        }
    }
}

// ---------------- small levels (rows <= 1024): barrier-free direct kernel ----------------
// One wave per 16-row x 16-ch output tile, owning ALL 5 gates (epilogue needs
// all gates for a (row,ch)). K=768 fully unrolled, 2-deep named-register
// pipeline, 6 loads + 5 MFMA per step. A (x/h slices <= 1.5 MB) and B (Wcat
// 2 MB) are L2/L3-hot at these sizes and grids are <= 256 blocks, so the
// R6-style contention failure does not apply; removes the 24-step barrier
// chain that dominated tiny levels.
__global__ __launch_bounds__(256)
void small_gemm(const unsigned short* __restrict__ xb,
                const unsigned short* __restrict__ Wcat,
                float* __restrict__ c_all,
                unsigned short* __restrict__ h_all,
                const float* __restrict__ b_i, const float* __restrict__ b_o,
                const float* __restrict__ b_u, const float* __restrict__ b_f,
                int lgM)
{
    const int tid = threadIdx.x, w = tid >> 6, lane = tid & 63;
    const int quad = lane >> 4, p = lane & 15;
    const int wid = blockIdx.x * 4 + w;
    const int mt = wid >> 4, ct = wid & 15;
    const int r0 = mt * 16, ch0 = ct * 16;
    const int M = 1 << lgM, s = M - 1, s2 = 2 * M - 1;

    const int arow = r0 + p, ab = arow >> lgM, am = arow & (M - 1);
    const unsigned short* axp = xb + ((size_t)ab * NN + s + am) * 256 + quad * 8;
    const unsigned short* ahL = h_all + ((size_t)ab * NN + s2 + 2 * am) * 256 + quad * 8;
    const unsigned short* ahR = ahL + 256;
    const unsigned short* bbp[5];
    #pragma unroll
    for (int j = 0; j < 5; ++j)
        bbp[j] = Wcat + (size_t)(j * 256 + ch0 + p) * 768 + quad * 8;

    f32x4_t acc[5];
    #pragma unroll
    for (int j = 0; j < 5; ++j) acc[j] = (f32x4_t){0.f, 0.f, 0.f, 0.f};

    bf16x8_t fa0, fa1, fb0[5], fb1[5];

    #define SLOAD(k0, fa, fb)                                                    \
        fa = *(const bf16x8_t*)((k0) < 256 ? (axp + (k0))                        \
                 : (k0) < 512 ? (ahL + ((k0) - 256)) : (ahR + ((k0) - 512)));    \
        _Pragma("unroll")                                                        \
        for (int j = 0; j < 5; ++j) fb[j] = *(const bf16x8_t*)(bbp[j] + (k0));
    #define SCOMP(fa, fb)                                                        \
        _Pragma("unroll")                                                        \
        for (int j = 0; j < 5; ++j)                                              \
            acc[j] = __builtin_amdgcn_mfma_f32_16x16x32_bf16(fa, fb[j], acc[j], 0, 0, 0);

    SLOAD(0, fa0, fb0);
    SLOAD(32, fa1, fb1);
    #pragma unroll
    for (int st = 0; st < 24; st += 2) {
        SCOMP(fa0, fb0);
        if (st + 2 < 24) { SLOAD((st + 2) * 32, fa0, fb0); }
        SCOMP(fa1, fb1);
        if (st + 3 < 24) { SLOAD((st + 3) * 32, fa1, fb1); }
    }
    #undef SLOAD
    #undef SCOMP

    // epilogue: lane owns ch = ch0+p, rows r0 + quad*4 + [0,4)
    const int gch = ch0 + p;
    const float bi = b_i[gch], bo = b_o[gch], bu = b_u[gch], bfv = b_f[gch];
    float cl[4], cr[4];
    #pragma unroll
    for (int reg = 0; reg < 4; ++reg) {
        const int grow = r0 + quad * 4 + reg;
        const int b = grow >> lgM, m = grow & (M - 1);
        const float* crow = c_all + ((size_t)b * NN + s2 + 2 * m) * 256 + gch;
        cl[reg] = crow[0];
        cr[reg] = crow[256];
    }
    #pragma unroll
    for (int reg = 0; reg < 4; ++reg) {
        const int grow = r0 + quad * 4 + reg;
        const int b = grow >> lgM, m = grow & (M - 1);
        float ig = sigmoidf_(acc[0][reg] + bi);
        float og = sigmoidf_(acc[1][reg] + bo);
        float ug = tanhf_(acc[2][reg] + bu);
        float f0 = sigmoidf_(acc[3][reg] + bfv);
        float f1 = sigmoidf_(acc[4][reg] + bfv);
        float c = fmaf(f0, cl[reg], fmaf(f1, cr[reg], ig * ug));
        float h = og * tanhf_(c);
        c_all[((size_t)b * NN + s + m) * 256 + gch] = c;
        h_all[((size_t)b * NN + s + m) * 256 + gch] = f2bf(h);
    }
}

// ---------------- classifier softmax over all nodes ----------------
__global__ __launch_bounds__(256)
void softmax_kernel(const unsigned short* __restrict__ h_all,
                    const float* __restrict__ W_s, const float* __restrict__ b_s,
                    float* __restrict__ out)
{
    __shared__ float Ws[5 * 256];
    int tid = threadIdx.x;
    for (int i = tid; i < 1280; i += 256) Ws[i] = W_s[i];
    __syncthreads();

    int r = tid >> 3, q = tid & 7;
    size_t row = (size_t)blockIdx.x * 32 + r;
    const unsigned short* hp = h_all + row * 256 + q * 32;

    float p0 = 0.f, p1 = 0.f, p2 = 0.f, p3 = 0.f, p4 = 0.f;
    #pragma unroll
    for (int kk = 0; kk < 32; kk += 8) {
        uint4 raw = *(const uint4*)(hp + kk);
        unsigned short hu[8];
        *(uint4*)hu = raw;
        #pragma unroll
        for (int e = 0; e < 8; ++e) {
            float hvv = bf2f(hu[e]);
            int k = q * 32 + kk + e;
            p0 = fmaf(Ws[k],        hvv, p0);
            p1 = fmaf(Ws[256 + k],  hvv, p1);
            p2 = fmaf(Ws[512 + k],  hvv, p2);
            p3 = fmaf(Ws[768 + k],  hvv, p3);
            p4 = fmaf(Ws[1024 + k], hvv, p4);
        }
    }
    #pragma unroll
    for (int off = 4; off; off >>= 1) {
        p0 += __shfl_down(p0, off, 8);
        p1 += __shfl_down(p1, off, 8);
        p2 += __shfl_down(p2, off, 8);
        p3 += __shfl_down(p3, off, 8);
        p4 += __shfl_down(p4, off, 8);
    }
    if (q == 0) {
        float l0 = p0 + b_s[0], l1 = p1 + b_s[1], l2 = p2 + b_s[2];
        float l3 = p3 + b_s[3], l4 = p4 + b_s[4];
        float mx = fmaxf(fmaxf(fmaxf(l0, l1), fmaxf(l2, l3)), l4);
        float e0 = __expf(l0 - mx), e1 = __expf(l1 - mx), e2 = __expf(l2 - mx);
        float e3 = __expf(l3 - mx), e4 = __expf(l4 - mx);
        float inv = 1.0f / (e0 + e1 + e2 + e3 + e4);
        float* orow = out + row * NCLASS;
        orow[0] = e0 * inv;
        orow[1] = e1 * inv;
        orow[2] = e2 * inv;
        orow[3] = e3 * inv;
        orow[4] = e4 * inv;
    }
}

extern "C" void kernel_launch(void* const* d_in, const int* in_sizes, int n_in,
                              void* d_out, int out_size, void* d_ws, size_t ws_size,
                              hipStream_t stream) {
    const float* x   = (const float*)d_in[0];
    const float* W_i = (const float*)d_in[1];
    const float* U_i = (const float*)d_in[2];
    const float* b_i = (const float*)d_in[3];
    const float* W_f = (const float*)d_in[4];
    const float* U_f = (const float*)d_in[5];
    const float* b_f = (const float*)d_in[6];
    const float* W_o = (const float*)d_in[7];
    const float* U_o = (const float*)d_in[8];
    const float* b_o = (const float*)d_in[9];
    const float* W_u = (const float*)d_in[10];
    const float* U_u = (const float*)d_in[11];
    const float* b_u = (const float*)d_in[12];
    const float* W_s = (const float*)d_in[13];
    const float* b_s = (const float*)d_in[14];
    float* out = (float*)d_out;

    char* p = (char*)d_ws;
    unsigned short* Wcat  = (unsigned short*)p; p += 2097152;       // 1280*768*2
    unsigned short* xb    = (unsigned short*)p; p += 134152192;     // 128*2047*256*2
    unsigned short* h_all = (unsigned short*)p; p += 134152192;     // 128*2047*256*2
    float*          c_all = (float*)p;          p += 268304384;     // 128*2047*256*4

    prep_wcat<<<3840, 256, 0, stream>>>(W_i, U_i, W_f, U_f, W_o, U_o, W_u, U_u, Wcat);
    cast_x_kernel<<<32752, 256, 0, stream>>>(x, xb);

    for (int lvl = DEPTH - 1; lvl >= 0; --lvl) {
        const int nrb = 1 << lvl;                       // rowblocks of 128
        if (lvl == DEPTH - 1) {
            level_gemm<3, 8, true><<<dim3(4 * nrb), 512, 0, stream>>>(
                xb, Wcat, c_all, h_all, b_i, b_o, b_u, b_f, lvl, nrb);
        } else if (lvl >= 4) {
            level_gemm<5, 24, false><<<dim3(4 * nrb), 512, 0, stream>>>(
                xb, Wcat, c_all, h_all, b_i, b_o, b_u, b_f, lvl, nrb);
        } else {
            // rows = 128<<lvl ; waves = rows (16x16 tiles x 16 ch-tiles) ; 4 waves/block
            small_gemm<<<dim3(32 << lvl), 256, 0, stream>>>(
                xb, Wcat, c_all, h_all, b_i, b_o, b_u, b_f, lvl);
        }
    }

    softmax_kernel<<<8188, 256, 0, stream>>>(h_all, W_s, b_s, out);
}